// Round 1
// baseline (456.672 us; speedup 1.0000x reference)
//
#include <hip/hip_runtime.h>

// Problem constants (from reference)
#define BB 8
#define PP 5000
#define DD 64
#define NBP (BB * PP)          // 40000 (b,p) pairs
#define WAVES_PER_BLOCK 4      // 256-thread blocks

// One 64-lane wave handles one (b,p) pair:
//   - a[d] = allele_table[al0][d] + allele_table[al1][d]   (lane d holds a[d])
//   - kernel row = 64x64 f32 = 1024 float4, read in 16 coalesced sweeps
//     (lane L reads float4 flat4 = i*64+L  ->  d = i*4 + (L>>4), e-quad = (L&15)*4)
//   - acc[e-quad] += a[d] * K[d][e-quad]  (a[d] fetched via __shfl)
//   - butterfly reduce over lanes differing in bits 4,5 (the 4 d-groups)
//   - lanes 0..15 add bias and store the 64-float output row (256 B coalesced)
__global__ __launch_bounds__(256) void allele_embed_kernel(
    const int* __restrict__ alleles,        // [NBP, 2]
    const int* __restrict__ positions,      // [NBP]
    const float* __restrict__ allele_table, // [16, 64]
    const float4* __restrict__ ktab4,       // [NPOS * 1024]
    const float4* __restrict__ btab4,       // [NPOS * 16]
    float4* __restrict__ out4)              // [NBP * 16]
{
    const int wave = threadIdx.x >> 6;
    const int lane = threadIdx.x & 63;
    const int bp   = blockIdx.x * WAVES_PER_BLOCK + wave;   // grid sized exactly

    // Wave-uniform scalars (same address across lanes -> broadcast load)
    const int al0 = alleles[bp * 2 + 0];
    const int al1 = alleles[bp * 2 + 1];
    const int pos = positions[bp];

    // lane d holds a[d]
    const float a_full = allele_table[al0 * DD + lane] + allele_table[al1 * DD + lane];

    const float4* __restrict__ krow = ktab4 + (size_t)pos * (DD * DD / 4);
    const int dg = lane >> 4;   // d-group 0..3

    float4 acc = make_float4(0.f, 0.f, 0.f, 0.f);
#pragma unroll
    for (int i = 0; i < 16; ++i) {
        const int d   = i * 4 + dg;
        const float ad = __shfl(a_full, d, 64);
        const float4 kv = krow[i * 64 + lane];
        acc.x += ad * kv.x;
        acc.y += ad * kv.y;
        acc.z += ad * kv.z;
        acc.w += ad * kv.w;
    }

    // Reduce the 4 d-group partials (lanes with equal lane&15)
#pragma unroll
    for (int off = 16; off <= 32; off <<= 1) {
        acc.x += __shfl_xor(acc.x, off, 64);
        acc.y += __shfl_xor(acc.y, off, 64);
        acc.z += __shfl_xor(acc.z, off, 64);
        acc.w += __shfl_xor(acc.w, off, 64);
    }

    if (lane < 16) {
        const float4 bv = btab4[(size_t)pos * (DD / 4) + lane];
        acc.x += bv.x;
        acc.y += bv.y;
        acc.z += bv.z;
        acc.w += bv.w;
        out4[(size_t)bp * (DD / 4) + lane] = acc;
    }
}

extern "C" void kernel_launch(void* const* d_in, const int* in_sizes, int n_in,
                              void* d_out, int out_size, void* d_ws, size_t ws_size,
                              hipStream_t stream) {
    const int*   alleles      = (const int*)d_in[0];
    const int*   positions    = (const int*)d_in[1];
    const float* allele_table = (const float*)d_in[2];
    const float4* ktab4       = (const float4*)d_in[3];
    const float4* btab4       = (const float4*)d_in[4];
    float4* out4              = (float4*)d_out;

    const int grid = NBP / WAVES_PER_BLOCK;  // 10000 blocks, exact
    allele_embed_kernel<<<grid, WAVES_PER_BLOCK * 64, 0, stream>>>(
        alleles, positions, allele_table, ktab4, btab4, out4);
}

// Round 2
// 452.441 us; speedup vs baseline: 1.0094x; 1.0094x over previous
//
#include <hip/hip_runtime.h>

// Problem constants (from reference)
#define BB 8
#define PP 5000
#define DD 64
#define NBP (BB * PP)          // 40000 (b,p) pairs
#define NPOSC 20000
#define WAVES_PER_BLOCK 4      // 256-thread blocks
#define GRID_MAIN (NBP / WAVES_PER_BLOCK)   // 10000 = 8 * 1250, exact

// Position bucketing for locality sort: bucket = pos >> 4  -> 1250 buckets
// (16 positions = 256 KB of kernel_table per bucket; fits L2 easily).
#define BSHIFT 4
#define NBUCKET 1250
#define NBUCKET_PAD 1280       // 256 threads x 5 chunk

// ---------------------------------------------------------------------------
// Prep 1: histogram of position buckets
__global__ __launch_bounds__(256) void hist_kernel(
    const int* __restrict__ positions, int* __restrict__ hist)
{
    const int tid = blockIdx.x * 256 + threadIdx.x;
    if (tid < NBP) atomicAdd(&hist[positions[tid] >> BSHIFT], 1);
}

// Prep 2: exclusive prefix sum over NBUCKET entries (single block).
__global__ __launch_bounds__(256) void scan_kernel(
    const int* __restrict__ hist, int* __restrict__ offs)
{
    __shared__ int lsum[256];
    const int t = threadIdx.x;
    const int base = t * 5;
    int v[5];
#pragma unroll
    for (int j = 0; j < 5; ++j)
        v[j] = (base + j < NBUCKET) ? hist[base + j] : 0;
    // exclusive prefix within chunk
    int run = 0;
#pragma unroll
    for (int j = 0; j < 5; ++j) { int x = v[j]; v[j] = run; run += x; }
    lsum[t] = run;
    __syncthreads();
    if (t == 0) {
        int acc = 0;
        for (int i = 0; i < 256; ++i) { int x = lsum[i]; lsum[i] = acc; acc += x; }
    }
    __syncthreads();
#pragma unroll
    for (int j = 0; j < 5; ++j)
        if (base + j < NBUCKET) offs[base + j] = lsum[t] + v[j];
}

// Prep 3: scatter bp indices into position-sorted order (order within a
// bucket is arbitrary -- fine, we only need temporal locality).
__global__ __launch_bounds__(256) void scatter_kernel(
    const int* __restrict__ positions, int* __restrict__ offs,
    int* __restrict__ order)
{
    const int tid = blockIdx.x * 256 + threadIdx.x;
    if (tid < NBP) {
        const int b = positions[tid] >> BSHIFT;
        const int idx = atomicAdd(&offs[b], 1);
        order[idx] = tid;
    }
}

// ---------------------------------------------------------------------------
// Main: one 64-lane wave per (b,p) pair, pairs consumed in position-sorted
// order. XCD swizzle: grid 10000 = 8 x 1250; blocks b === x (mod 8) land on
// XCD x (round-robin dispatch heuristic) and cover contiguous work range
// [x*1250, (x+1)*1250) -> same-position reuse stays within one XCD's L2.
//
//   - a[d] = allele_table[al0][d] + allele_table[al1][d]   (lane d holds a[d])
//   - kernel row = 64x64 f32 = 1024 float4, read in 16 coalesced sweeps
//     (lane L reads float4 flat4 = i*64+L  ->  d = i*4 + (L>>4), e-quad = (L&15)*4)
//   - acc[e-quad] += a[d] * K[d][e-quad]  (a[d] via __shfl)
//   - butterfly reduce over lanes differing in bits 4,5
//   - lanes 0..15 add bias and store the 64-float output row (256 B)
__global__ __launch_bounds__(256) void allele_embed_kernel(
    const int* __restrict__ alleles,        // [NBP, 2]
    const int* __restrict__ positions,      // [NBP]
    const float* __restrict__ allele_table, // [16, 64]
    const float4* __restrict__ ktab4,       // [NPOS * 1024]
    const float4* __restrict__ btab4,       // [NPOS * 16]
    const int* __restrict__ order,          // [NBP] position-sorted bp ids
    float4* __restrict__ out4)              // [NBP * 16]
{
    const int wave = threadIdx.x >> 6;
    const int lane = threadIdx.x & 63;
    // XCD swizzle: contiguous work per XCD
    const int work = (blockIdx.x & 7) * (GRID_MAIN / 8) + (blockIdx.x >> 3);
    const int bp   = order[work * WAVES_PER_BLOCK + wave];

    const int al0 = alleles[bp * 2 + 0];
    const int al1 = alleles[bp * 2 + 1];
    const int pos = positions[bp];

    const float a_full = allele_table[al0 * DD + lane] + allele_table[al1 * DD + lane];

    const float4* __restrict__ krow = ktab4 + (size_t)pos * (DD * DD / 4);
    const int dg = lane >> 4;   // d-group 0..3

    float4 acc = make_float4(0.f, 0.f, 0.f, 0.f);
#pragma unroll
    for (int i = 0; i < 16; ++i) {
        const int d    = i * 4 + dg;
        const float ad = __shfl(a_full, d, 64);
        const float4 kv = krow[i * 64 + lane];
        acc.x += ad * kv.x;
        acc.y += ad * kv.y;
        acc.z += ad * kv.z;
        acc.w += ad * kv.w;
    }

#pragma unroll
    for (int off = 16; off <= 32; off <<= 1) {
        acc.x += __shfl_xor(acc.x, off, 64);
        acc.y += __shfl_xor(acc.y, off, 64);
        acc.z += __shfl_xor(acc.z, off, 64);
        acc.w += __shfl_xor(acc.w, off, 64);
    }

    if (lane < 16) {
        const float4 bv = btab4[(size_t)pos * (DD / 4) + lane];
        acc.x += bv.x;
        acc.y += bv.y;
        acc.z += bv.z;
        acc.w += bv.w;
        out4[(size_t)bp * (DD / 4) + lane] = acc;
    }
}

extern "C" void kernel_launch(void* const* d_in, const int* in_sizes, int n_in,
                              void* d_out, int out_size, void* d_ws, size_t ws_size,
                              hipStream_t stream) {
    const int*   alleles      = (const int*)d_in[0];
    const int*   positions    = (const int*)d_in[1];
    const float* allele_table = (const float*)d_in[2];
    const float4* ktab4       = (const float4*)d_in[3];
    const float4* btab4       = (const float4*)d_in[4];
    float4* out4              = (float4*)d_out;

    // Workspace layout (ints): hist[1280] | offs[1280] | order[40000]
    int* hist  = (int*)d_ws;
    int* offs  = hist + NBUCKET_PAD;
    int* order = offs + NBUCKET_PAD;

    // hist must start zeroed (ws is poisoned to 0xAA before every launch)
    hipMemsetAsync(hist, 0, NBUCKET_PAD * sizeof(int), stream);

    const int gprep = (NBP + 255) / 256;
    hist_kernel<<<gprep, 256, 0, stream>>>(positions, hist);
    scan_kernel<<<1, 256, 0, stream>>>(hist, offs);
    scatter_kernel<<<gprep, 256, 0, stream>>>(positions, offs, order);

    allele_embed_kernel<<<GRID_MAIN, WAVES_PER_BLOCK * 64, 0, stream>>>(
        alleles, positions, allele_table, ktab4, btab4, order, out4);
}